// Round 1
// baseline (328.216 us; speedup 1.0000x reference)
//
#include <hip/hip_runtime.h>
#include <cstddef>

#define NSAMP 128
#define WAVES_PER_BLOCK 4

__global__ __launch_bounds__(256) void volrend_kernel(
    const float* __restrict__ sig,   // [n_rays, 128]
    const float* __restrict__ rad,   // [n_rays, 128, 3]
    const float* __restrict__ zv,    // [128]
    float* __restrict__ rgb,         // [n_rays, 3]
    float* __restrict__ depth,       // [n_rays]
    float* __restrict__ wts,         // [n_rays, 128]
    int n_rays)
{
    const int lane = threadIdx.x & 63;
    const int ray  = blockIdx.x * WAVES_PER_BLOCK + (threadIdx.x >> 6);
    if (ray >= n_rays) return;

    const int za = lane;        // z in [0,64)
    const int zb = lane + 64;   // z in [64,128)

    // z_vals and dists (dists[z] = zv[min(z+1,127)] - zv[min(z,126)])
    const float z_a = zv[za];
    const float z_b = zv[zb];
    const float dist_a = zv[za + 1] - z_a;                       // za+1 <= 64
    const float dist_b = zv[min(zb + 1, 127)] - zv[min(zb, 126)];

    // sigma -> alpha and survival factor f = (1 - alpha + 1e-10) = exp(-x) + 1e-10
    const float* sray = sig + (size_t)ray * NSAMP;
    const float sa = sray[za];
    const float sb = sray[zb];
    const float ea = expf(-fmaxf(sa, 0.0f) * dist_a);
    const float eb = expf(-fmaxf(sb, 0.0f) * dist_b);
    const float alpha_a = 1.0f - ea;
    const float alpha_b = 1.0f - eb;
    const float fa = ea + 1e-10f;
    const float fb = eb + 1e-10f;

    // Exclusive cumprod of f across 128 z-samples (wave-wide scan).
    // First half: inclusive Hillis-Steele scan of fa over lanes 0..63.
    float p = fa;
    #pragma unroll
    for (int d = 1; d < 64; d <<= 1) {
        float t = __shfl_up(p, d);
        if (lane >= d) p *= t;
    }
    float Ta = __shfl_up(p, 1);           // exclusive
    if (lane == 0) Ta = 1.0f;
    const float Tfull = __shfl(p, 63);    // product of f[0..63]

    // Second half: scan of fb, prefixed by Tfull.
    float q = fb;
    #pragma unroll
    for (int d = 1; d < 64; d <<= 1) {
        float t = __shfl_up(q, d);
        if (lane >= d) q *= t;
    }
    float Tb = __shfl_up(q, 1);
    Tb = (lane == 0) ? Tfull : Tb * Tfull;

    const float wa = alpha_a * Ta;
    const float wb = alpha_b * Tb;

    // weights out (coalesced 4B/lane)
    float* wray = wts + (size_t)ray * NSAMP;
    wray[za] = wa;
    wray[zb] = wb;

    // rgb + depth partial sums
    const float* rray = rad + (size_t)ray * (NSAMP * 3);
    float s0 = wa * rray[3 * za + 0] + wb * rray[3 * zb + 0];
    float s1 = wa * rray[3 * za + 1] + wb * rray[3 * zb + 1];
    float s2 = wa * rray[3 * za + 2] + wb * rray[3 * zb + 2];
    float s3 = wa * z_a + wb * z_b;

    // wave-wide butterfly reduction (64 lanes)
    #pragma unroll
    for (int d = 32; d > 0; d >>= 1) {
        s0 += __shfl_xor(s0, d);
        s1 += __shfl_xor(s1, d);
        s2 += __shfl_xor(s2, d);
        s3 += __shfl_xor(s3, d);
    }
    if (lane == 0) {
        rgb[(size_t)ray * 3 + 0] = s0;
        rgb[(size_t)ray * 3 + 1] = s1;
        rgb[(size_t)ray * 3 + 2] = s2;
        depth[ray] = s3;
    }
}

extern "C" void kernel_launch(void* const* d_in, const int* in_sizes, int n_in,
                              void* d_out, int out_size, void* d_ws, size_t ws_size,
                              hipStream_t stream) {
    const float* sig = (const float*)d_in[0];   // [B,R,128,1] f32
    const float* rad = (const float*)d_in[1];   // [B,R,128,3] f32
    const float* zv  = (const float*)d_in[2];   // [128] f32

    const int n_rays = in_sizes[0] / NSAMP;     // B*R = 131072

    float* rgb   = (float*)d_out;                         // n_rays*3
    float* depth = rgb + (size_t)n_rays * 3;              // n_rays
    float* wts   = depth + (size_t)n_rays;                // n_rays*128

    const int blocks = (n_rays + WAVES_PER_BLOCK - 1) / WAVES_PER_BLOCK;
    volrend_kernel<<<blocks, 64 * WAVES_PER_BLOCK, 0, stream>>>(
        sig, rad, zv, rgb, depth, wts, n_rays);
}

// Round 3
// 312.745 us; speedup vs baseline: 1.0495x; 1.0495x over previous
//
#include <hip/hip_runtime.h>
#include <cstddef>

#define NSAMP 128
#define WPB 4   // waves (= rays) per block

typedef float f32x2 __attribute__((ext_vector_type(2)));

__global__ __launch_bounds__(256) void volrend_kernel(
    const float* __restrict__ sig,   // [n_rays, 128]
    const float* __restrict__ rad,   // [n_rays, 128, 3]
    const float* __restrict__ zv,    // [128]
    float* __restrict__ rgb,         // [n_rays, 3]
    float* __restrict__ depth,       // [n_rays]
    float* __restrict__ wts,         // [n_rays, 128]
    int n_rays)
{
    __shared__ float lds[WPB][384];  // one radiance row per wave

    const int lane = threadIdx.x & 63;
    const int wid  = threadIdx.x >> 6;
    int ray = blockIdx.x * WPB + wid;
    if (ray >= n_rays) ray = n_rays - 1;   // duplicate work on tail, benign

    const int z0 = 2 * lane;               // this lane owns z0, z0+1

    // --- stage radiance row into LDS (coalesced 8B loads, 512B x3 per wave) ---
    const f32x2* rrow = (const f32x2*)(rad + (size_t)ray * 384);
    f32x2 r0 = __builtin_nontemporal_load(rrow + lane);
    f32x2 r1 = __builtin_nontemporal_load(rrow + 64 + lane);
    f32x2 r2 = __builtin_nontemporal_load(rrow + 128 + lane);
    f32x2* lrow = (f32x2*)lds[wid];
    lrow[lane]       = r0;
    lrow[64 + lane]  = r1;
    lrow[128 + lane] = r2;

    // --- sigma: one coalesced 8B load ---
    const f32x2 sv = __builtin_nontemporal_load(
        (const f32x2*)(sig + (size_t)ray * NSAMP) + lane);

    // --- z values and dists ---
    const f32x2 z01 = *((const f32x2*)zv + lane);   // zv[z0], zv[z0+1]
    const float z2  = zv[min(z0 + 2, 127)];
    const float d0  = z01.y - z01.x;                // dist for z0 (z0+1<=127)
    const float d1  = (z0 + 1 < 127) ? (z2 - z01.y) : d0;

    // --- alpha & survival f = exp(-relu(sigma)*dist) + 1e-10 ---
    const float e0 = __expf(-fmaxf(sv.x, 0.0f) * d0);
    const float e1 = __expf(-fmaxf(sv.y, 0.0f) * d1);
    const float a0 = 1.0f - e0;
    const float a1 = 1.0f - e1;
    const float f0 = e0 + 1e-10f;
    const float f1 = e1 + 1e-10f;

    // --- exclusive cumprod over 128 samples via one 64-lane scan of pair products ---
    float p = f0 * f1;
    #pragma unroll
    for (int d = 1; d < 64; d <<= 1) {
        float t = __shfl_up(p, d);
        if (lane >= d) p *= t;
    }
    float E = __shfl_up(p, 1);      // exclusive prefix = T(2l)
    if (lane == 0) E = 1.0f;

    const float w0 = a0 * E;
    const float w1 = a1 * (E * f0);

    // --- weights out: coalesced 8B store ---
    f32x2 wv; wv.x = w0; wv.y = w1;
    __builtin_nontemporal_store(wv, (f32x2*)(wts + (size_t)ray * NSAMP) + lane);

    // --- read this lane's 6 radiance floats from LDS ---
    __syncthreads();
    const float* lp = lds[wid] + 6 * lane;   // r0 g0 b0 r1 g1 b1
    float s0 = w0 * lp[0] + w1 * lp[3];
    float s1 = w0 * lp[1] + w1 * lp[4];
    float s2 = w0 * lp[2] + w1 * lp[5];
    float s3 = w0 * z01.x + w1 * z01.y;

    // --- 10-shuffle 4-value reduction ---
    s0 += __shfl_xor(s0, 32);
    s1 += __shfl_xor(s1, 32);
    s2 += __shfl_xor(s2, 32);
    s3 += __shfl_xor(s3, 32);
    float A = (lane & 32) ? s2 : s0;
    float B = (lane & 32) ? s3 : s1;
    A += __shfl_xor(A, 16);
    B += __shfl_xor(B, 16);
    float v = (lane & 16) ? B : A;
    v += __shfl_xor(v, 8);
    v += __shfl_xor(v, 4);
    v += __shfl_xor(v, 2);
    v += __shfl_xor(v, 1);

    if ((lane & 15) == 0) {
        const int c = lane >> 4;   // 0,1,2 -> rgb ; 3 -> depth
        if (c < 3) rgb[(size_t)ray * 3 + c] = v;
        else       depth[ray] = v;
    }
}

extern "C" void kernel_launch(void* const* d_in, const int* in_sizes, int n_in,
                              void* d_out, int out_size, void* d_ws, size_t ws_size,
                              hipStream_t stream) {
    const float* sig = (const float*)d_in[0];   // [B,R,128,1] f32
    const float* rad = (const float*)d_in[1];   // [B,R,128,3] f32
    const float* zv  = (const float*)d_in[2];   // [128] f32

    const int n_rays = in_sizes[0] / NSAMP;     // B*R = 131072

    float* rgb   = (float*)d_out;               // n_rays*3
    float* depth = rgb + (size_t)n_rays * 3;    // n_rays
    float* wts   = depth + (size_t)n_rays;      // n_rays*128

    const int blocks = (n_rays + WPB - 1) / WPB;
    volrend_kernel<<<blocks, 64 * WPB, 0, stream>>>(
        sig, rad, zv, rgb, depth, wts, n_rays);
}

// Round 4
// 311.511 us; speedup vs baseline: 1.0536x; 1.0040x over previous
//
#include <hip/hip_runtime.h>
#include <cstddef>

#define NSAMP 128
#define WPB 4   // waves per block; each wave = 2 rays

typedef float f32x4 __attribute__((ext_vector_type(4)));

__global__ __launch_bounds__(256) void volrend_kernel(
    const float* __restrict__ sig,   // [n_rays, 128]
    const float* __restrict__ rad,   // [n_rays, 128, 3]
    const float* __restrict__ zv,    // [128]
    float* __restrict__ rgb,         // [n_rays, 3]
    float* __restrict__ depth,       // [n_rays]
    float* __restrict__ wts,         // [n_rays, 128]
    int n_pairs)                     // n_rays / 2
{
    __shared__ float lds[WPB][768];  // 2 radiance rows per wave (own region, no barrier)

    const int lane = threadIdx.x & 63;
    const int wid  = threadIdx.x >> 6;
    int rp = blockIdx.x * WPB + wid;
    if (rp >= n_pairs) rp = n_pairs - 1;     // duplicate tail work, benign

    const int sl  = lane & 31;               // lane within 32-lane segment (one ray each)
    const int ray = 2 * rp + (lane >> 5);

    // --- stage both rays' radiance (3072 B contiguous) into LDS, dwordx4 ---
    const f32x4* rbase = (const f32x4*)(rad + (size_t)rp * 768);
    f32x4 r0 = __builtin_nontemporal_load(rbase + lane);
    f32x4 r1 = __builtin_nontemporal_load(rbase + 64 + lane);
    f32x4 r2 = __builtin_nontemporal_load(rbase + 128 + lane);
    f32x4* lrow = (f32x4*)lds[wid];
    lrow[lane]       = r0;
    lrow[64 + lane]  = r1;
    lrow[128 + lane] = r2;

    // --- sigma: both rays, 1024 B contiguous, one dwordx4 per lane ---
    const f32x4 sv = __builtin_nontemporal_load(
        (const f32x4*)(sig + (size_t)rp * 256) + lane);

    // --- z values (this lane owns z = 4sl .. 4sl+3) and dists ---
    const f32x4 z4 = *((const f32x4*)zv + sl);
    const float zn = zv[min(4 * sl + 4, 127)];
    const float d0 = z4.y - z4.x;
    const float d1 = z4.z - z4.y;
    const float d2 = z4.w - z4.z;
    const float d3 = (sl == 31) ? d2 : (zn - z4.w);

    // --- alpha & survival f = exp(-relu(sigma)*dist) + 1e-10 ---
    const float e0 = __expf(-fmaxf(sv.x, 0.0f) * d0);
    const float e1 = __expf(-fmaxf(sv.y, 0.0f) * d1);
    const float e2 = __expf(-fmaxf(sv.z, 0.0f) * d2);
    const float e3 = __expf(-fmaxf(sv.w, 0.0f) * d3);
    const float f0 = e0 + 1e-10f;
    const float f1 = e1 + 1e-10f;
    const float f2 = e2 + 1e-10f;
    const float f3 = e3 + 1e-10f;

    // --- intra-lane prefix products, then segmented 32-lane scan of 4-products ---
    const float F1 = f0;
    const float F2 = f0 * f1;
    const float F3 = F2 * f2;
    float p = F3 * f3;
    #pragma unroll
    for (int d = 1; d < 32; d <<= 1) {
        float t = __shfl_up(p, d);           // full-wave shfl; guard keeps segments apart
        if (sl >= d) p *= t;
    }
    float E = __shfl_up(p, 1);               // exclusive prefix for this lane's block
    if (sl == 0) E = 1.0f;

    const float w0 = (1.0f - e0) * E;
    const float w1 = (1.0f - e1) * (E * F1);
    const float w2 = (1.0f - e2) * (E * F2);
    const float w3 = (1.0f - e3) * (E * F3);

    // --- weights out: one dwordx4 store, both rays contiguous ---
    f32x4 wv; wv.x = w0; wv.y = w1; wv.z = w2; wv.w = w3;
    __builtin_nontemporal_store(wv, (f32x4*)(wts + (size_t)rp * 256) + lane);

    // --- this lane's 12 radiance floats from LDS (48 B, 16B-aligned) ---
    const f32x4* lp = (const f32x4*)(lds[wid] + (lane >> 5) * 384 + sl * 12);
    const f32x4 ra = lp[0];   // r0 g0 b0 r1
    const f32x4 rb = lp[1];   // g1 b1 r2 g2
    const f32x4 rc = lp[2];   // b2 r3 g3 b3
    float s0 = w0 * ra.x + w1 * ra.w + w2 * rb.z + w3 * rc.y;
    float s1 = w0 * ra.y + w1 * rb.x + w2 * rb.w + w3 * rc.z;
    float s2 = w0 * ra.z + w1 * rb.y + w2 * rc.x + w3 * rc.w;
    float s3 = w0 * z4.x + w1 * z4.y + w2 * z4.z + w3 * z4.w;

    // --- 9-shuffle 4-value reduction over each 32-lane segment (both rays at once) ---
    s0 += __shfl_xor(s0, 16);
    s1 += __shfl_xor(s1, 16);
    s2 += __shfl_xor(s2, 16);
    s3 += __shfl_xor(s3, 16);
    float A = (sl & 16) ? s2 : s0;
    float B = (sl & 16) ? s3 : s1;
    A += __shfl_xor(A, 8);
    B += __shfl_xor(B, 8);
    float C = (sl & 8) ? B : A;
    C += __shfl_xor(C, 4);
    C += __shfl_xor(C, 2);
    C += __shfl_xor(C, 1);

    if ((sl & 7) == 0) {
        const int c = sl >> 3;               // 0,1,2 -> rgb ; 3 -> depth
        if (c < 3) rgb[(size_t)ray * 3 + c] = C;
        else       depth[ray] = C;
    }
}

extern "C" void kernel_launch(void* const* d_in, const int* in_sizes, int n_in,
                              void* d_out, int out_size, void* d_ws, size_t ws_size,
                              hipStream_t stream) {
    const float* sig = (const float*)d_in[0];   // [B,R,128,1] f32
    const float* rad = (const float*)d_in[1];   // [B,R,128,3] f32
    const float* zv  = (const float*)d_in[2];   // [128] f32

    const int n_rays  = in_sizes[0] / NSAMP;    // B*R = 131072 (even)
    const int n_pairs = n_rays / 2;

    float* rgb   = (float*)d_out;               // n_rays*3
    float* depth = rgb + (size_t)n_rays * 3;    // n_rays
    float* wts   = depth + (size_t)n_rays;      // n_rays*128

    const int blocks = (n_pairs + WPB - 1) / WPB;
    volrend_kernel<<<blocks, 64 * WPB, 0, stream>>>(
        sig, rad, zv, rgb, depth, wts, n_pairs);
}